// Round 4
// baseline (995.436 us; speedup 1.0000x reference)
//
#include <hip/hip_runtime.h>

#define S_LEN   2048
#define HID_DIM 4096
#define NHEADS  32
#define NKVH    8
#define HD      128
#define KV_DIM  1024
#define BS_ROWS 4096   // B * S

typedef __attribute__((ext_vector_type(4))) float f32x4;
typedef __attribute__((ext_vector_type(8))) short bf16x8;

// ---------------- helpers ----------------
__device__ __forceinline__ unsigned short f2b(float f) {
  union { float f; unsigned int u; } cv; cv.f = f;
  unsigned int r = (cv.u + 0x7FFFu + ((cv.u >> 16) & 1u)) >> 16;  // RNE
  return (unsigned short)r;
}
__device__ __forceinline__ float b2f(unsigned short u) {
  union { unsigned int u; float f; } cv; cv.u = ((unsigned int)u) << 16; return cv.f;
}
__device__ __forceinline__ void gload_lds16(const void* g, void* l) {
  __builtin_amdgcn_global_load_lds(
      (const __attribute__((address_space(1))) unsigned int*)g,
      (__attribute__((address_space(3))) unsigned int*)l, 16, 0, 0);
}
__device__ __forceinline__ void store_out(float* p, float v) { *p = v; }
__device__ __forceinline__ void store_out(unsigned short* p, float v) { *p = f2b(v); }

// ---------------- f32 -> bf16 convert ----------------
__global__ void cvt_f32_bf16(const float* __restrict__ in, unsigned short* __restrict__ out, int n4) {
  int i = blockIdx.x * blockDim.x + threadIdx.x;
  if (i >= n4) return;
  f32x4 v = reinterpret_cast<const f32x4*>(in)[i];
  ushort4 o;
  o.x = f2b(v[0]); o.y = f2b(v[1]); o.z = f2b(v[2]); o.w = f2b(v[3]);
  reinterpret_cast<ushort4*>(out)[i] = o;
}

// ------- transpose + convert: W (K x N) f32 -> Wt (N x K) bf16 -------
__global__ void transpose_cvt(const float* __restrict__ W, unsigned short* __restrict__ Wt,
                              int K, int N) {
  __shared__ float t[32][33];
  int n0 = blockIdx.x * 32, k0 = blockIdx.y * 32;
  int tx = threadIdx.x, ty = threadIdx.y;
#pragma unroll
  for (int i = 0; i < 4; ++i)
    t[ty + 8 * i][tx] = W[(size_t)(k0 + ty + 8 * i) * N + n0 + tx];
  __syncthreads();
#pragma unroll
  for (int i = 0; i < 4; ++i)
    Wt[(size_t)(n0 + ty + 8 * i) * K + k0 + tx] = f2b(t[tx][ty + 8 * i]);
}

// ------- V transpose (bf16): Vb[4096][1024] -> Vt[(b*8+kvh)*128 + d][s] (2048x2048) -------
__global__ void transpose_v_k(const unsigned short* __restrict__ Vb, unsigned short* __restrict__ Vt) {
  __shared__ unsigned short t[32][33];
  int c0 = blockIdx.x * 32;   // col base 0..1023
  int r0 = blockIdx.y * 32;   // row base 0..4095
  int tx = threadIdx.x, ty = threadIdx.y;
#pragma unroll
  for (int i = 0; i < 4; ++i)
    t[ty + 8 * i][tx] = Vb[(size_t)(r0 + ty + 8 * i) * KV_DIM + c0 + tx];
  __syncthreads();
  int ob = (r0 >> 11) * 1024;   // b * 1024
  int oc = r0 & 2047;           // s base
#pragma unroll
  for (int i = 0; i < 4; ++i)
    Vt[(size_t)(ob + c0 + ty + 8 * i) * S_LEN + oc + tx] = t[tx][ty + 8 * i];
}

// ---------------- RoPE tables (f32, accurate trig) ----------------
__global__ void rope_table_k(float* __restrict__ cosT, float* __restrict__ sinT) {
  int idx = blockIdx.x * blockDim.x + threadIdx.x;
  if (idx >= S_LEN * 64) return;
  int s = idx >> 6, i = idx & 63;
  float inv = 1.0f / powf(10000.0f, (float)(2 * i) * (1.0f / 128.0f));
  float ang = (float)s * inv;
  cosT[idx] = cosf(ang);
  sinT[idx] = sinf(ang);
}

// ---------------- RoPE apply (in place, bf16) ----------------
__global__ void rope_apply_k(unsigned short* __restrict__ X, const float* __restrict__ cosT,
                             const float* __restrict__ sinT, int nheads, float scale, int total) {
  int idx = blockIdx.x * blockDim.x + threadIdx.x;
  if (idx >= total) return;
  int i = idx & 63;
  int t = idx >> 6;
  int h = t % nheads;
  int row = t / nheads;          // 0..BS_ROWS-1, row = b*S + s
  int s = row & (S_LEN - 1);
  float c = cosT[(s << 6) + i], sn = sinT[(s << 6) + i];
  size_t base = (size_t)row * ((size_t)nheads * HD) + (size_t)h * HD;
  float x1 = b2f(X[base + i]);
  float x2 = b2f(X[base + 64 + i]);
  X[base + i]      = f2b((x1 * c - x2 * sn) * scale);
  X[base + 64 + i] = f2b((x2 * c + x1 * sn) * scale);
}

// ---------------- bf16 MFMA GEMM: C(MxN) = A(MxK) * Bt(NxK)^T ----------------
template <typename OutT>
__global__ __launch_bounds__(256) void gemm_bt(const unsigned short* __restrict__ A,
                                               const unsigned short* __restrict__ Bt,
                                               OutT* __restrict__ C, int M, int N, int K) {
  __shared__ unsigned short As[128 * 32];
  __shared__ unsigned short Bs[128 * 32];
  const int tid = threadIdx.x;
  const int lane = tid & 63;
  const int wave = tid >> 6;
  int nwg = gridDim.x, wg = blockIdx.x;
  int swz = (nwg % 8 == 0) ? ((wg & 7) * (nwg >> 3) + (wg >> 3)) : wg;
  const int nbn = N >> 7;
  const int bm = swz / nbn, bn = swz % nbn;
  const int m0 = bm << 7, n0 = bn << 7;
  const int wr = wave >> 1, wc = wave & 1;
  const int lr = lane & 15, kb = lane >> 4;

  f32x4 acc[4][4];
#pragma unroll
  for (int i = 0; i < 4; ++i)
#pragma unroll
    for (int j = 0; j < 4; ++j) acc[i][j] = (f32x4){0.f, 0.f, 0.f, 0.f};

  const unsigned short* Ab = A + (size_t)m0 * K;
  const unsigned short* Bb = Bt + (size_t)n0 * K;

  for (int k0 = 0; k0 < K; k0 += 32) {
    __syncthreads();
#pragma unroll
    for (int i = 0; i < 2; ++i) {
      int idx = i * 256 + tid;
      int row = idx >> 2;
      int off = (idx & 3) << 3;
      gload_lds16(Ab + (size_t)row * K + k0 + off, As + row * 32 + off);
      gload_lds16(Bb + (size_t)row * K + k0 + off, Bs + row * 32 + off);
    }
    __syncthreads();

    bf16x8 af[4], bfr[4];
#pragma unroll
    for (int mi = 0; mi < 4; ++mi)
      af[mi] = *reinterpret_cast<const bf16x8*>(As + (wr * 64 + mi * 16 + lr) * 32 + kb * 8);
#pragma unroll
    for (int ni = 0; ni < 4; ++ni)
      bfr[ni] = *reinterpret_cast<const bf16x8*>(Bs + (wc * 64 + ni * 16 + lr) * 32 + kb * 8);
#pragma unroll
    for (int mi = 0; mi < 4; ++mi)
#pragma unroll
      for (int ni = 0; ni < 4; ++ni)
        acc[mi][ni] = __builtin_amdgcn_mfma_f32_16x16x32_bf16(af[mi], bfr[ni], acc[mi][ni], 0, 0, 0);
  }

#pragma unroll
  for (int mi = 0; mi < 4; ++mi)
#pragma unroll
    for (int ni = 0; ni < 4; ++ni)
#pragma unroll
      for (int r = 0; r < 4; ++r) {
        int row = m0 + wr * 64 + mi * 16 + kb * 4 + r;
        int col = n0 + wc * 64 + ni * 16 + lr;
        store_out(&C[(size_t)row * N + col], acc[mi][ni][r]);
      }
}

// ---------------- flash attention (causal, GQA 32/8, D=128) ----------------
// 4 waves x 16 q-rows (QBLK=64), KV step 32, paired q-tiles (uniform 66 steps/block).
// K: double-buffered LDS, source-XOR-swizzled global_load_lds, ONE barrier/step (T3-min).
// V: pre-transposed global Vt[d][s]; B-frags via 8x global b128 loads/step (L1-resident).
// P: per-wave LDS round-trip (proven layout). Defer-max rescale (T13, THR=8).
__global__ __launch_bounds__(256) void attn_fwd(const unsigned short* __restrict__ Q,
                                                const unsigned short* __restrict__ K,
                                                const unsigned short* __restrict__ Vt,
                                                unsigned short* __restrict__ O) {
  __shared__ unsigned short Ks[2][32 * 128];
  __shared__ unsigned short Ps[4][16 * 32];
  const int tid = threadIdx.x, lane = tid & 63, wave = tid >> 6;
  const int lr = lane & 15, kb = lane >> 4;
  const int pr = blockIdx.x;           // 0..15 (pair index)
  const int bh = blockIdx.y;           // 0..63
  const int b = bh >> 5, h = bh & 31, kvh = h >> 2;
  const unsigned short* Qp = Q + (size_t)b * S_LEN * HID_DIM + (size_t)h * HD;
  const unsigned short* Kp = K + (size_t)b * S_LEN * KV_DIM + (size_t)kvh * HD;
  const unsigned short* Vtp = Vt + (size_t)(b * 8 + kvh) * HD * S_LEN;  // [128][2048]
  unsigned short* Op = O + (size_t)b * S_LEN * HID_DIM + (size_t)h * HD;

#pragma unroll 1
  for (int pass = 0; pass < 2; ++pass) {
    const int qt = pass ? pr : 31 - pr;
    const int q0 = qt * 64;

    // Q A-fragments: row = lane&15, k = kb*8+j within each 32-d chunk
    bf16x8 qf[4];
    const int qrow = q0 + wave * 16 + lr;
#pragma unroll
    for (int dc = 0; dc < 4; ++dc)
      qf[dc] = *reinterpret_cast<const bf16x8*>(Qp + (size_t)qrow * HID_DIM + dc * 32 + kb * 8);

    f32x4 of[8];
#pragma unroll
    for (int i = 0; i < 8; ++i) of[i] = (f32x4){0.f, 0.f, 0.f, 0.f};
    float mrow[4] = {-3.0e38f, -3.0e38f, -3.0e38f, -3.0e38f};
    float lrow[4] = {0.f, 0.f, 0.f, 0.f};

    const int nsteps = (q0 + 64) >> 5;

    // prologue: stage tile 0 into Ks[0]
#pragma unroll
    for (int i = 0; i < 2; ++i) {
      int c = i * 256 + tid;
      int key = c >> 4;
      int ch = (c & 15) ^ (key & 7);
      gload_lds16(Kp + (size_t)key * KV_DIM + ch * 8, &Ks[0][0] + c * 8);
    }
    __syncthreads();  // drains vmcnt; tile 0 visible

#pragma unroll 1
    for (int t = 0; t < nsteps; ++t) {
      const int kv0 = t << 5;
      const unsigned short* Kcur = &Ks[t & 1][0];

      // --- prefetch next K tile into the other buffer (overlaps with compute)
      if (t + 1 < nsteps) {
        unsigned short* Knxt = &Ks[(t + 1) & 1][0];
#pragma unroll
        for (int i = 0; i < 2; ++i) {
          int c = i * 256 + tid;
          int key = c >> 4;
          int ch = (c & 15) ^ (key & 7);
          gload_lds16(Kp + (size_t)(kv0 + 32 + key) * KV_DIM + ch * 8, Knxt + c * 8);
        }
      }

      // --- S = Q K^T (two 16-key fragments), swizzled K reads
      f32x4 sf[2];
      sf[0] = (f32x4){0.f, 0.f, 0.f, 0.f};
      sf[1] = (f32x4){0.f, 0.f, 0.f, 0.f};
      __builtin_amdgcn_s_setprio(1);
#pragma unroll
      for (int ki = 0; ki < 2; ++ki)
#pragma unroll
        for (int dc = 0; dc < 4; ++dc) {
          int key = ki * 16 + lr;
          bf16x8 kf = *reinterpret_cast<const bf16x8*>(
              Kcur + key * 128 + (((dc * 4 + kb) ^ (lr & 7)) << 3));
          sf[ki] = __builtin_amdgcn_mfma_f32_16x16x32_bf16(qf[dc], kf, sf[ki], 0, 0, 0);
        }
      __builtin_amdgcn_s_setprio(0);

      // --- issue V fragment loads early (latency hides under softmax)
      bf16x8 vf[8];
#pragma unroll
      for (int dc2 = 0; dc2 < 8; ++dc2)
        vf[dc2] = *reinterpret_cast<const bf16x8*>(
            Vtp + (size_t)(dc2 * 16 + lr) * S_LEN + kv0 + kb * 8);

      // --- online softmax with defer-max (THR=8); C layout row=(lane>>4)*4+r, col=lane&15
#pragma unroll
      for (int r = 0; r < 4; ++r) {
        int qg = q0 + wave * 16 + kb * 4 + r;
        float s0 = sf[0][r]; if (kv0 + lr > qg)      s0 = -3.0e38f;
        float s1 = sf[1][r]; if (kv0 + 16 + lr > qg) s1 = -3.0e38f;
        float m = fmaxf(s0, s1);
#pragma unroll
        for (int o = 1; o < 16; o <<= 1) m = fmaxf(m, __shfl_xor(m, o));
        if (m > mrow[r] + 8.0f) {   // rescale path (rare after warm-up)
          float corr = __expf(mrow[r] - m);
          lrow[r] *= corr;
#pragma unroll
          for (int dc2 = 0; dc2 < 8; ++dc2) of[dc2][r] *= corr;
          mrow[r] = m;
        }
        float p0 = __expf(s0 - mrow[r]);   // bounded by e^8
        float p1 = __expf(s1 - mrow[r]);
        float rs = p0 + p1;
#pragma unroll
        for (int o = 1; o < 16; o <<= 1) rs += __shfl_xor(rs, o);
        lrow[r] += rs;
        Ps[wave][(kb * 4 + r) * 32 + lr]      = f2b(p0);
        Ps[wave][(kb * 4 + r) * 32 + 16 + lr] = f2b(p1);
      }
      // Ps is per-wave private: wave-local LDS drain suffices (no block barrier)
      asm volatile("s_waitcnt lgkmcnt(0)" ::: "memory");
      __builtin_amdgcn_sched_barrier(0);

      // --- O += P V : A-frag from Ps, B-frag = preloaded vf (global Vt)
      bf16x8 pf = *reinterpret_cast<const bf16x8*>(&Ps[wave][lr * 32 + kb * 8]);
      __builtin_amdgcn_s_setprio(1);
#pragma unroll
      for (int dc2 = 0; dc2 < 8; ++dc2)
        of[dc2] = __builtin_amdgcn_mfma_f32_16x16x32_bf16(pf, vf[dc2], of[dc2], 0, 0, 0);
      __builtin_amdgcn_s_setprio(0);

      __syncthreads();  // one barrier/step: drains next-tile staging; all Kcur reads done
    }

    // --- normalize + write
#pragma unroll
    for (int dc2 = 0; dc2 < 8; ++dc2)
#pragma unroll
      for (int r = 0; r < 4; ++r) {
        int qg = q0 + wave * 16 + kb * 4 + r;
        Op[(size_t)qg * HID_DIM + dc2 * 16 + lr] = f2b(of[dc2][r] / lrow[r]);
      }
  }
}

// ---------------- launch ----------------
extern "C" void kernel_launch(void* const* d_in, const int* in_sizes, int n_in,
                              void* d_out, int out_size, void* d_ws, size_t ws_size,
                              hipStream_t stream) {
  const float* x  = (const float*)d_in[0];
  const float* Wq = (const float*)d_in[2];
  const float* Wk = (const float*)d_in[3];
  const float* Wv = (const float*)d_in[4];
  const float* Wo = (const float*)d_in[5];
  float* out = (float*)d_out;

  char* ws = (char*)d_ws;
  unsigned short* xb  = (unsigned short*)(ws + 0);          // 33.5MB (later reused as AO)
  unsigned short* wtb = (unsigned short*)(ws + 33554432);   // Wq^T, later Wo^T
  unsigned short* wkt = (unsigned short*)(ws + 67108864);   // Wk^T, later Vt (8.4MB)
  unsigned short* wvt = (unsigned short*)(ws + 75497472);
  unsigned short* Qb  = (unsigned short*)(ws + 83886080);
  unsigned short* Kb  = (unsigned short*)(ws + 117440512);
  unsigned short* Vb  = (unsigned short*)(ws + 125829120);
  float* cosT = (float*)(ws + 134217728);
  float* sinT = (float*)(ws + 134742016);
  unsigned short* AO  = xb;   // alias: x dead after V projection
  unsigned short* Vtb = wkt;  // alias: Wk^T dead after K projection

  cvt_f32_bf16<<<16384, 256, 0, stream>>>(x, xb, (BS_ROWS * HID_DIM) / 4);
  transpose_cvt<<<dim3(128, 128), dim3(32, 8), 0, stream>>>(Wq, wtb, HID_DIM, HID_DIM);
  transpose_cvt<<<dim3(32, 128), dim3(32, 8), 0, stream>>>(Wk, wkt, HID_DIM, KV_DIM);
  transpose_cvt<<<dim3(32, 128), dim3(32, 8), 0, stream>>>(Wv, wvt, HID_DIM, KV_DIM);
  rope_table_k<<<512, 256, 0, stream>>>(cosT, sinT);

  gemm_bt<unsigned short><<<1024, 256, 0, stream>>>(xb, wtb, Qb, BS_ROWS, HID_DIM, HID_DIM);
  gemm_bt<unsigned short><<<256, 256, 0, stream>>>(xb, wkt, Kb, BS_ROWS, KV_DIM, HID_DIM);
  gemm_bt<unsigned short><<<256, 256, 0, stream>>>(xb, wvt, Vb, BS_ROWS, KV_DIM, HID_DIM);

  transpose_v_k<<<dim3(32, 128), dim3(32, 8), 0, stream>>>(Vb, Vtb);     // wkt dead now
  transpose_cvt<<<dim3(128, 128), dim3(32, 8), 0, stream>>>(Wo, wtb, HID_DIM, HID_DIM);

  rope_apply_k<<<32768, 256, 0, stream>>>(Qb, cosT, sinT, NHEADS, 0.08838834764831843f,
                                          BS_ROWS * NHEADS * 64);
  rope_apply_k<<<8192, 256, 0, stream>>>(Kb, cosT, sinT, NKVH, 1.0f, BS_ROWS * NKVH * 64);

  attn_fwd<<<dim3(16, 64), 256, 0, stream>>>(Qb, Kb, Vtb, AO);

  gemm_bt<float><<<1024, 256, 0, stream>>>(AO, wtb, out, BS_ROWS, HID_DIM, HID_DIM);
}

// Round 5
// 794.200 us; speedup vs baseline: 1.2534x; 1.2534x over previous
//
#include <hip/hip_runtime.h>

#define S_LEN   2048
#define HID_DIM 4096
#define NHEADS  32
#define NKVH    8
#define HD      128
#define KV_DIM  1024
#define BS_ROWS 4096   // B * S

typedef __attribute__((ext_vector_type(4))) float f32x4;
typedef __attribute__((ext_vector_type(8))) short bf16x8;

// ---------------- helpers ----------------
__device__ __forceinline__ unsigned short f2b(float f) {
  union { float f; unsigned int u; } cv; cv.f = f;
  unsigned int r = (cv.u + 0x7FFFu + ((cv.u >> 16) & 1u)) >> 16;  // RNE
  return (unsigned short)r;
}
__device__ __forceinline__ float b2f(unsigned short u) {
  union { unsigned int u; float f; } cv; cv.u = ((unsigned int)u) << 16; return cv.f;
}
__device__ __forceinline__ void gload_lds16(const void* g, void* l) {
  __builtin_amdgcn_global_load_lds(
      (const __attribute__((address_space(1))) unsigned int*)g,
      (__attribute__((address_space(3))) unsigned int*)l, 16, 0, 0);
}
__device__ __forceinline__ void store_out(float* p, float v) { *p = v; }
__device__ __forceinline__ void store_out(unsigned short* p, float v) { *p = f2b(v); }

// ---------------- f32 -> bf16 convert ----------------
__global__ void cvt_f32_bf16(const float* __restrict__ in, unsigned short* __restrict__ out, int n4) {
  int i = blockIdx.x * blockDim.x + threadIdx.x;
  if (i >= n4) return;
  f32x4 v = reinterpret_cast<const f32x4*>(in)[i];
  ushort4 o;
  o.x = f2b(v[0]); o.y = f2b(v[1]); o.z = f2b(v[2]); o.w = f2b(v[3]);
  reinterpret_cast<ushort4*>(out)[i] = o;
}

// ------- transpose + convert: W (K x N) f32 -> Wt (N x K) bf16 -------
__global__ void transpose_cvt(const float* __restrict__ W, unsigned short* __restrict__ Wt,
                              int K, int N) {
  __shared__ float t[32][33];
  int n0 = blockIdx.x * 32, k0 = blockIdx.y * 32;
  int tx = threadIdx.x, ty = threadIdx.y;
#pragma unroll
  for (int i = 0; i < 4; ++i)
    t[ty + 8 * i][tx] = W[(size_t)(k0 + ty + 8 * i) * N + n0 + tx];
  __syncthreads();
#pragma unroll
  for (int i = 0; i < 4; ++i)
    Wt[(size_t)(n0 + ty + 8 * i) * K + k0 + tx] = f2b(t[tx][ty + 8 * i]);
}

// ---------------- RoPE tables (f32, accurate trig) ----------------
__global__ void rope_table_k(float* __restrict__ cosT, float* __restrict__ sinT) {
  int idx = blockIdx.x * blockDim.x + threadIdx.x;
  if (idx >= S_LEN * 64) return;
  int s = idx >> 6, i = idx & 63;
  float inv = 1.0f / powf(10000.0f, (float)(2 * i) * (1.0f / 128.0f));
  float ang = (float)s * inv;
  cosT[idx] = cosf(ang);
  sinT[idx] = sinf(ang);
}

// ---------------- RoPE apply (in place, bf16) ----------------
__global__ void rope_apply_k(unsigned short* __restrict__ X, const float* __restrict__ cosT,
                             const float* __restrict__ sinT, int nheads, float scale, int total) {
  int idx = blockIdx.x * blockDim.x + threadIdx.x;
  if (idx >= total) return;
  int i = idx & 63;
  int t = idx >> 6;
  int h = t % nheads;
  int row = t / nheads;          // 0..BS_ROWS-1, row = b*S + s
  int s = row & (S_LEN - 1);
  float c = cosT[(s << 6) + i], sn = sinT[(s << 6) + i];
  size_t base = (size_t)row * ((size_t)nheads * HD) + (size_t)h * HD;
  float x1 = b2f(X[base + i]);
  float x2 = b2f(X[base + 64 + i]);
  X[base + i]      = f2b((x1 * c - x2 * sn) * scale);
  X[base + 64 + i] = f2b((x2 * c + x1 * sn) * scale);
}

// ---------------- 128-tile bf16 MFMA GEMM (m97 structure) — used for K/V proj ----
template <typename OutT>
__global__ __launch_bounds__(256) void gemm_bt(const unsigned short* __restrict__ A,
                                               const unsigned short* __restrict__ Bt,
                                               OutT* __restrict__ C, int M, int N, int K) {
  __shared__ unsigned short As[128 * 32];
  __shared__ unsigned short Bs[128 * 32];
  const int tid = threadIdx.x;
  const int lane = tid & 63;
  const int wave = tid >> 6;
  int nwg = gridDim.x, wg = blockIdx.x;
  int swz = (nwg % 8 == 0) ? ((wg & 7) * (nwg >> 3) + (wg >> 3)) : wg;
  const int nbn = N >> 7;
  const int bm = swz / nbn, bn = swz % nbn;
  const int m0 = bm << 7, n0 = bn << 7;
  const int wr = wave >> 1, wc = wave & 1;
  const int lr = lane & 15, kb = lane >> 4;

  f32x4 acc[4][4];
#pragma unroll
  for (int i = 0; i < 4; ++i)
#pragma unroll
    for (int j = 0; j < 4; ++j) acc[i][j] = (f32x4){0.f, 0.f, 0.f, 0.f};

  const unsigned short* Ab = A + (size_t)m0 * K;
  const unsigned short* Bb = Bt + (size_t)n0 * K;

  for (int k0 = 0; k0 < K; k0 += 32) {
    __syncthreads();
#pragma unroll
    for (int i = 0; i < 2; ++i) {
      int idx = i * 256 + tid;
      int row = idx >> 2;
      int off = (idx & 3) << 3;
      gload_lds16(Ab + (size_t)row * K + k0 + off, As + row * 32 + off);
      gload_lds16(Bb + (size_t)row * K + k0 + off, Bs + row * 32 + off);
    }
    __syncthreads();

    bf16x8 af[4], bfr[4];
#pragma unroll
    for (int mi = 0; mi < 4; ++mi)
      af[mi] = *reinterpret_cast<const bf16x8*>(As + (wr * 64 + mi * 16 + lr) * 32 + kb * 8);
#pragma unroll
    for (int ni = 0; ni < 4; ++ni)
      bfr[ni] = *reinterpret_cast<const bf16x8*>(Bs + (wc * 64 + ni * 16 + lr) * 32 + kb * 8);
#pragma unroll
    for (int mi = 0; mi < 4; ++mi)
#pragma unroll
      for (int ni = 0; ni < 4; ++ni)
        acc[mi][ni] = __builtin_amdgcn_mfma_f32_16x16x32_bf16(af[mi], bfr[ni], acc[mi][ni], 0, 0, 0);
  }

#pragma unroll
  for (int mi = 0; mi < 4; ++mi)
#pragma unroll
    for (int ni = 0; ni < 4; ++ni)
#pragma unroll
      for (int r = 0; r < 4; ++r) {
        int row = m0 + wr * 64 + mi * 16 + kb * 4 + r;
        int col = n0 + wc * 64 + ni * 16 + lr;
        store_out(&C[(size_t)row * N + col], acc[mi][ni][r]);
      }
}

// ---------------- 256-tile 8-wave 4-phase GEMM (T2+T3+T4+T5) — Q/O proj ----------
// BM=BN=256, BK=64, 512 threads (2M x 4N waves), per-wave 128x64 out, acc[8][4].
// LDS 128KiB double-buffered. Raw s_barrier + counted vmcnt: staging loads stay
// in flight across phase barriers; single vmcnt(0) at tile boundary.
// Bank swizzle: chunk-XOR (ch ^= row&7) pre-applied on global source, applied on read.
#define STAGE_HALF(dstBase, Sp, k0, h)                                           \
  {                                                                              \
    _Pragma("unroll")                                                            \
    for (int i_ = 0; i_ < 2; ++i_) {                                             \
      int c_ = i_ * 512 + tid;                                                   \
      int rl_ = c_ >> 3, ch_ = c_ & 7;                                           \
      int row_ = (h) * 128 + rl_;                                                \
      gload_lds16((Sp) + (size_t)row_ * K + (k0) + ((ch_ ^ (row_ & 7)) << 3),    \
                  (char*)(dstBase) + row_ * 128 + ch_ * 16);                     \
    }                                                                            \
  }
#define LDF(buf, R, sw) \
  (*reinterpret_cast<const bf16x8*>((const char*)(buf) + (R) * 128 + (sw)))
#define PHASE_SYNC()                                        \
  __builtin_amdgcn_s_barrier();                             \
  asm volatile("s_waitcnt lgkmcnt(0)" ::: "memory");        \
  __builtin_amdgcn_sched_barrier(0);

template <typename OutT>
__global__ __launch_bounds__(512, 1) void gemm256(const unsigned short* __restrict__ A,
                                                  const unsigned short* __restrict__ Bt,
                                                  OutT* __restrict__ C, int M, int N, int K) {
  __shared__ unsigned short Asl[2][256 * 64];
  __shared__ unsigned short Bsl[2][256 * 64];
  const int tid = threadIdx.x;
  const int lane = tid & 63;
  const int wave = tid >> 6;       // 0..7
  const int wr = wave >> 2;        // 0..1  (M)
  const int wc = wave & 3;         // 0..3  (N)
  const int lr = lane & 15, kb = lane >> 4;

  int nwg = gridDim.x, wg = blockIdx.x;
  int swz = (nwg % 8 == 0) ? ((wg & 7) * (nwg >> 3) + (wg >> 3)) : wg;
  const int nbn = N >> 8;
  const int bm = swz / nbn, bn = swz % nbn;
  const int m0 = bm << 8, n0 = bn << 8;

  const unsigned short* Ab = A + (size_t)m0 * K;
  const unsigned short* Bb = Bt + (size_t)n0 * K;

  f32x4 acc[8][4];
#pragma unroll
  for (int i = 0; i < 8; ++i)
#pragma unroll
    for (int j = 0; j < 4; ++j) acc[i][j] = (f32x4){0.f, 0.f, 0.f, 0.f};

  // per-thread swizzled k-chunk byte offsets for kk=0,1  (rows of interest have R&7 == lr&7)
  const int sw0 = ((kb) ^ (lr & 7)) << 4;
  const int sw1 = ((4 + kb) ^ (lr & 7)) << 4;

  // prologue: stage tile 0 fully, full drain once
  STAGE_HALF(Asl[0], Ab, 0, 0); STAGE_HALF(Asl[0], Ab, 0, 1);
  STAGE_HALF(Bsl[0], Bb, 0, 0); STAGE_HALF(Bsl[0], Bb, 0, 1);
  __syncthreads();

  const int nt = K >> 6;
  bf16x8 af[4], bfr[4];

#pragma unroll 1
  for (int t = 0; t < nt; ++t) {
    const unsigned short* Acur = Asl[t & 1];
    const unsigned short* Bcur = Bsl[t & 1];
    unsigned short* Anxt = Asl[(t + 1) & 1];
    unsigned short* Bnxt = Bsl[(t + 1) & 1];
    const int k0n = (t + 1) << 6;
    const bool pf = (t + 1 < nt);

    // ---- phase 0: (mh=0, kk=0); stage A(t+1)
#pragma unroll
    for (int ni = 0; ni < 4; ++ni) bfr[ni] = LDF(Bcur, wc * 64 + ni * 16 + lr, sw0);
#pragma unroll
    for (int mi = 0; mi < 4; ++mi) af[mi] = LDF(Acur, wr * 128 + mi * 16 + lr, sw0);
    if (pf) { STAGE_HALF(Anxt, Ab, k0n, 0); STAGE_HALF(Anxt, Ab, k0n, 1); }
    PHASE_SYNC();
    __builtin_amdgcn_s_setprio(1);
#pragma unroll
    for (int mi = 0; mi < 4; ++mi)
#pragma unroll
      for (int ni = 0; ni < 4; ++ni)
        acc[mi][ni] = __builtin_amdgcn_mfma_f32_16x16x32_bf16(af[mi], bfr[ni], acc[mi][ni], 0, 0, 0);
    __builtin_amdgcn_s_setprio(0);
    __builtin_amdgcn_s_barrier();

    // ---- phase 1: (mh=1, kk=0); stage B(t+1)
#pragma unroll
    for (int mi = 0; mi < 4; ++mi) af[mi] = LDF(Acur, wr * 128 + (mi + 4) * 16 + lr, sw0);
    if (pf) { STAGE_HALF(Bnxt, Bb, k0n, 0); STAGE_HALF(Bnxt, Bb, k0n, 1); }
    PHASE_SYNC();
    __builtin_amdgcn_s_setprio(1);
#pragma unroll
    for (int mi = 0; mi < 4; ++mi)
#pragma unroll
      for (int ni = 0; ni < 4; ++ni)
        acc[mi + 4][ni] = __builtin_amdgcn_mfma_f32_16x16x32_bf16(af[mi], bfr[ni], acc[mi + 4][ni], 0, 0, 0);
    __builtin_amdgcn_s_setprio(0);
    __builtin_amdgcn_s_barrier();

    // ---- phase 2: (mh=0, kk=1)
#pragma unroll
    for (int ni = 0; ni < 4; ++ni) bfr[ni] = LDF(Bcur, wc * 64 + ni * 16 + lr, sw1);
#pragma unroll
    for (int mi = 0; mi < 4; ++mi) af[mi] = LDF(Acur, wr * 128 + mi * 16 + lr, sw1);
    PHASE_SYNC();
    __builtin_amdgcn_s_setprio(1);
#pragma unroll
    for (int mi = 0; mi < 4; ++mi)
#pragma unroll
      for (int ni = 0; ni < 4; ++ni)
        acc[mi][ni] = __builtin_amdgcn_mfma_f32_16x16x32_bf16(af[mi], bfr[ni], acc[mi][ni], 0, 0, 0);
    __builtin_amdgcn_s_setprio(0);
    __builtin_amdgcn_s_barrier();

    // ---- phase 3: (mh=1, kk=1)
#pragma unroll
    for (int mi = 0; mi < 4; ++mi) af[mi] = LDF(Acur, wr * 128 + (mi + 4) * 16 + lr, sw1);
    PHASE_SYNC();
    __builtin_amdgcn_s_setprio(1);
#pragma unroll
    for (int mi = 0; mi < 4; ++mi)
#pragma unroll
      for (int ni = 0; ni < 4; ++ni)
        acc[mi + 4][ni] = __builtin_amdgcn_mfma_f32_16x16x32_bf16(af[mi], bfr[ni], acc[mi + 4][ni], 0, 0, 0);
    __builtin_amdgcn_s_setprio(0);
    __builtin_amdgcn_s_barrier();

    // ---- tile boundary: staged t+1 must be resident before t+1 phase-0 ds_reads
    if (pf) asm volatile("s_waitcnt vmcnt(0)" ::: "memory");
    __builtin_amdgcn_s_barrier();
  }

  // epilogue: C/D layout col=lane&15, row=(lane>>4)*4+reg
#pragma unroll
  for (int mi = 0; mi < 8; ++mi)
#pragma unroll
    for (int ni = 0; ni < 4; ++ni)
#pragma unroll
      for (int r = 0; r < 4; ++r) {
        int row = m0 + wr * 128 + mi * 16 + kb * 4 + r;
        int col = n0 + wc * 64 + ni * 16 + lr;
        store_out(&C[(size_t)row * N + col], acc[mi][ni][r]);
      }
}

// ---------------- flash attention (causal, GQA 32/8, D=128) ----------------
// Round-2 proven version: 4 waves x 16 q-rows, KV step 32, paired q-tiles.
// K LDS: linear rows, SOURCE chunk-XOR-swizzled. V: direct global scalar reads.
__global__ __launch_bounds__(256) void attn_fwd(const unsigned short* __restrict__ Q,
                                                const unsigned short* __restrict__ K,
                                                const unsigned short* __restrict__ V,
                                                unsigned short* __restrict__ O) {
  __shared__ unsigned short Ks[32 * 128];
  __shared__ unsigned short Ps[4][16 * 32];
  const int tid = threadIdx.x, lane = tid & 63, wave = tid >> 6;
  const int lr = lane & 15, kb = lane >> 4;
  const int pr = blockIdx.x;           // 0..15 (pair index)
  const int bh = blockIdx.y;           // 0..63
  const int b = bh >> 5, h = bh & 31, kvh = h >> 2;
  const unsigned short* Qp = Q + (size_t)b * S_LEN * HID_DIM + (size_t)h * HD;
  const unsigned short* Kp = K + (size_t)b * S_LEN * KV_DIM + (size_t)kvh * HD;
  const unsigned short* Vp = V + (size_t)b * S_LEN * KV_DIM + (size_t)kvh * HD;
  unsigned short* Op = O + (size_t)b * S_LEN * HID_DIM + (size_t)h * HD;

#pragma unroll 1
  for (int pass = 0; pass < 2; ++pass) {
    const int qt = pass ? pr : 31 - pr;
    const int q0 = qt * 64;

    bf16x8 qf[4];
    const int qrow = q0 + wave * 16 + lr;
#pragma unroll
    for (int dc = 0; dc < 4; ++dc)
      qf[dc] = *reinterpret_cast<const bf16x8*>(Qp + (size_t)qrow * HID_DIM + dc * 32 + kb * 8);

    f32x4 of[8];
#pragma unroll
    for (int i = 0; i < 8; ++i) of[i] = (f32x4){0.f, 0.f, 0.f, 0.f};
    float mrow[4] = {-3.0e38f, -3.0e38f, -3.0e38f, -3.0e38f};
    float lrow[4] = {0.f, 0.f, 0.f, 0.f};

    const int kvend = q0 + 64;
    for (int kv0 = 0; kv0 < kvend; kv0 += 32) {
      __syncthreads();
#pragma unroll
      for (int i = 0; i < 2; ++i) {
        int c = i * 256 + tid;
        int key = c >> 4;
        int ch = (c & 15) ^ (key & 7);
        gload_lds16(Kp + (size_t)(kv0 + key) * KV_DIM + ch * 8, Ks + c * 8);
      }
      __syncthreads();

      f32x4 sf[2];
      sf[0] = (f32x4){0.f, 0.f, 0.f, 0.f};
      sf[1] = (f32x4){0.f, 0.f, 0.f, 0.f};
#pragma unroll
      for (int ki = 0; ki < 2; ++ki)
#pragma unroll
        for (int dc = 0; dc < 4; ++dc) {
          int key = ki * 16 + lr;
          bf16x8 kf = *reinterpret_cast<const bf16x8*>(
              Ks + key * 128 + (((dc * 4 + kb) ^ (lr & 7)) << 3));
          sf[ki] = __builtin_amdgcn_mfma_f32_16x16x32_bf16(qf[dc], kf, sf[ki], 0, 0, 0);
        }

#pragma unroll
      for (int r = 0; r < 4; ++r) {
        int qg = q0 + wave * 16 + kb * 4 + r;
        float s0 = sf[0][r]; if (kv0 + lr > qg)      s0 = -3.0e38f;
        float s1 = sf[1][r]; if (kv0 + 16 + lr > qg) s1 = -3.0e38f;
        float m = fmaxf(s0, s1);
#pragma unroll
        for (int o = 1; o < 16; o <<= 1) m = fmaxf(m, __shfl_xor(m, o));
        float mn = fmaxf(mrow[r], m);
        float p0 = __expf(s0 - mn);
        float p1 = __expf(s1 - mn);
        float rs = p0 + p1;
#pragma unroll
        for (int o = 1; o < 16; o <<= 1) rs += __shfl_xor(rs, o);
        float corr = __expf(mrow[r] - mn);
        lrow[r] = lrow[r] * corr + rs;
        mrow[r] = mn;
        Ps[wave][(kb * 4 + r) * 32 + lr]      = f2b(p0);
        Ps[wave][(kb * 4 + r) * 32 + 16 + lr] = f2b(p1);
#pragma unroll
        for (int dc2 = 0; dc2 < 8; ++dc2) of[dc2][r] *= corr;
      }
      asm volatile("s_waitcnt lgkmcnt(0)" ::: "memory");
      __builtin_amdgcn_sched_barrier(0);

      bf16x8 pf = *reinterpret_cast<const bf16x8*>(&Ps[wave][lr * 32 + kb * 8]);
      const unsigned short* Vr0 = Vp + (size_t)(kv0 + kb * 8) * KV_DIM;
#pragma unroll
      for (int g = 0; g < 2; ++g) {
        bf16x8 vf[4];
#pragma unroll
        for (int dh = 0; dh < 4; ++dh) {
          int dc2 = g * 4 + dh;
#pragma unroll
          for (int j = 0; j < 8; ++j)
            vf[dh][j] = (short)Vr0[(size_t)j * KV_DIM + dc2 * 16 + lr];
        }
#pragma unroll
        for (int dh = 0; dh < 4; ++dh)
          of[g * 4 + dh] = __builtin_amdgcn_mfma_f32_16x16x32_bf16(pf, vf[dh], of[g * 4 + dh], 0, 0, 0);
      }
    }

#pragma unroll
    for (int dc2 = 0; dc2 < 8; ++dc2)
#pragma unroll
      for (int r = 0; r < 4; ++r) {
        int qg = q0 + wave * 16 + kb * 4 + r;
        Op[(size_t)qg * HID_DIM + dc2 * 16 + lr] = f2b(of[dc2][r] / lrow[r]);
      }
  }
}

// ---------------- launch ----------------
extern "C" void kernel_launch(void* const* d_in, const int* in_sizes, int n_in,
                              void* d_out, int out_size, void* d_ws, size_t ws_size,
                              hipStream_t stream) {
  const float* x  = (const float*)d_in[0];
  const float* Wq = (const float*)d_in[2];
  const float* Wk = (const float*)d_in[3];
  const float* Wv = (const float*)d_in[4];
  const float* Wo = (const float*)d_in[5];
  float* out = (float*)d_out;

  char* ws = (char*)d_ws;
  unsigned short* xb  = (unsigned short*)(ws + 0);          // 33.5MB (later reused as AO)
  unsigned short* wtb = (unsigned short*)(ws + 33554432);   // Wq^T, later Wo^T
  unsigned short* wkt = (unsigned short*)(ws + 67108864);
  unsigned short* wvt = (unsigned short*)(ws + 75497472);
  unsigned short* Qb  = (unsigned short*)(ws + 83886080);
  unsigned short* Kb  = (unsigned short*)(ws + 117440512);
  unsigned short* Vb  = (unsigned short*)(ws + 125829120);
  float* cosT = (float*)(ws + 134217728);
  float* sinT = (float*)(ws + 134742016);
  unsigned short* AO = xb;  // alias: x dead after V projection

  cvt_f32_bf16<<<16384, 256, 0, stream>>>(x, xb, (BS_ROWS * HID_DIM) / 4);
  transpose_cvt<<<dim3(128, 128), dim3(32, 8), 0, stream>>>(Wq, wtb, HID_DIM, HID_DIM);
  transpose_cvt<<<dim3(32, 128), dim3(32, 8), 0, stream>>>(Wk, wkt, HID_DIM, KV_DIM);
  transpose_cvt<<<dim3(32, 128), dim3(32, 8), 0, stream>>>(Wv, wvt, HID_DIM, KV_DIM);
  rope_table_k<<<512, 256, 0, stream>>>(cosT, sinT);

  gemm256<unsigned short><<<256, 512, 0, stream>>>(xb, wtb, Qb, BS_ROWS, HID_DIM, HID_DIM);
  gemm_bt<unsigned short><<<256, 256, 0, stream>>>(xb, wkt, Kb, BS_ROWS, KV_DIM, HID_DIM);
  gemm_bt<unsigned short><<<256, 256, 0, stream>>>(xb, wvt, Vb, BS_ROWS, KV_DIM, HID_DIM);

  transpose_cvt<<<dim3(128, 128), dim3(32, 8), 0, stream>>>(Wo, wtb, HID_DIM, HID_DIM);

  rope_apply_k<<<32768, 256, 0, stream>>>(Qb, cosT, sinT, NHEADS, 0.08838834764831843f,
                                          BS_ROWS * NHEADS * 64);
  rope_apply_k<<<8192, 256, 0, stream>>>(Kb, cosT, sinT, NKVH, 1.0f, BS_ROWS * NKVH * 64);

  attn_fwd<<<dim3(16, 64), 256, 0, stream>>>(Qb, Kb, Vb, AO);

  gemm256<float><<<256, 512, 0, stream>>>(AO, wtb, out, BS_ROWS, HID_DIM, HID_DIM);
}

// Round 6
// 684.300 us; speedup vs baseline: 1.4547x; 1.1606x over previous
//
#include <hip/hip_runtime.h>

#define S_LEN   2048
#define HID_DIM 4096
#define NHEADS  32
#define NKVH    8
#define HD      128
#define KV_DIM  1024
#define KV2     2048   // fused K|V row stride
#define BS_ROWS 4096   // B * S

typedef __attribute__((ext_vector_type(4))) float f32x4;
typedef __attribute__((ext_vector_type(8))) short bf16x8;

// ---------------- helpers ----------------
__device__ __forceinline__ unsigned short f2b(float f) {
  union { float f; unsigned int u; } cv; cv.f = f;
  unsigned int r = (cv.u + 0x7FFFu + ((cv.u >> 16) & 1u)) >> 16;  // RNE
  return (unsigned short)r;
}
__device__ __forceinline__ float b2f(unsigned short u) {
  union { unsigned int u; float f; } cv; cv.u = ((unsigned int)u) << 16; return cv.f;
}
__device__ __forceinline__ void gload_lds16(const void* g, void* l) {
  __builtin_amdgcn_global_load_lds(
      (const __attribute__((address_space(1))) unsigned int*)g,
      (__attribute__((address_space(3))) unsigned int*)l, 16, 0, 0);
}
__device__ __forceinline__ void store_out(float* p, float v) { *p = v; }
__device__ __forceinline__ void store_out(unsigned short* p, float v) { *p = f2b(v); }

// ---------------- f32 -> bf16 convert ----------------
__global__ void cvt_f32_bf16(const float* __restrict__ in, unsigned short* __restrict__ out, int n4) {
  int i = blockIdx.x * blockDim.x + threadIdx.x;
  if (i >= n4) return;
  f32x4 v = reinterpret_cast<const f32x4*>(in)[i];
  ushort4 o;
  o.x = f2b(v[0]); o.y = f2b(v[1]); o.z = f2b(v[2]); o.w = f2b(v[3]);
  reinterpret_cast<ushort4*>(out)[i] = o;
}

// ------- transpose + convert: W (K x N) f32 -> Wt (N x K) bf16 -------
__global__ void transpose_cvt(const float* __restrict__ W, unsigned short* __restrict__ Wt,
                              int K, int N) {
  __shared__ float t[32][33];
  int n0 = blockIdx.x * 32, k0 = blockIdx.y * 32;
  int tx = threadIdx.x, ty = threadIdx.y;
#pragma unroll
  for (int i = 0; i < 4; ++i)
    t[ty + 8 * i][tx] = W[(size_t)(k0 + ty + 8 * i) * N + n0 + tx];
  __syncthreads();
#pragma unroll
  for (int i = 0; i < 4; ++i)
    Wt[(size_t)(n0 + ty + 8 * i) * K + k0 + tx] = f2b(t[tx][ty + 8 * i]);
}

// ---------------- RoPE tables (f32, accurate trig) ----------------
__global__ void rope_table_k(float* __restrict__ cosT, float* __restrict__ sinT) {
  int idx = blockIdx.x * blockDim.x + threadIdx.x;
  if (idx >= S_LEN * 64) return;
  int s = idx >> 6, i = idx & 63;
  float inv = 1.0f / powf(10000.0f, (float)(2 * i) * (1.0f / 128.0f));
  float ang = (float)s * inv;
  cosT[idx] = cosf(ang);
  sinT[idx] = sinf(ang);
}

// ---------------- RoPE apply (in place, bf16, strided) ----------------
__global__ void rope_apply_k(unsigned short* __restrict__ X, const float* __restrict__ cosT,
                             const float* __restrict__ sinT, int nheads, int rowstride,
                             float scale, int total) {
  int idx = blockIdx.x * blockDim.x + threadIdx.x;
  if (idx >= total) return;
  int i = idx & 63;
  int t = idx >> 6;
  int h = t % nheads;
  int row = t / nheads;          // 0..BS_ROWS-1, row = b*S + s
  int s = row & (S_LEN - 1);
  float c = cosT[(s << 6) + i], sn = sinT[(s << 6) + i];
  size_t base = (size_t)row * rowstride + (size_t)h * HD;
  float x1 = b2f(X[base + i]);
  float x2 = b2f(X[base + 64 + i]);
  X[base + i]      = f2b((x1 * c - x2 * sn) * scale);
  X[base + 64 + i] = f2b((x2 * c + x1 * sn) * scale);
}

// ---------------- 128-tile bf16 MFMA GEMM (m97 structure) — KV proj ----------
template <typename OutT>
__global__ __launch_bounds__(256) void gemm_bt(const unsigned short* __restrict__ A,
                                               const unsigned short* __restrict__ Bt,
                                               OutT* __restrict__ C, int M, int N, int K) {
  __shared__ unsigned short As[128 * 32];
  __shared__ unsigned short Bs[128 * 32];
  const int tid = threadIdx.x;
  const int lane = tid & 63;
  const int wave = tid >> 6;
  int nwg = gridDim.x, wg = blockIdx.x;
  int swz = (nwg % 8 == 0) ? ((wg & 7) * (nwg >> 3) + (wg >> 3)) : wg;
  const int nbn = N >> 7;
  const int bm = swz / nbn, bn = swz % nbn;
  const int m0 = bm << 7, n0 = bn << 7;
  const int wr = wave >> 1, wc = wave & 1;
  const int lr = lane & 15, kb = lane >> 4;

  f32x4 acc[4][4];
#pragma unroll
  for (int i = 0; i < 4; ++i)
#pragma unroll
    for (int j = 0; j < 4; ++j) acc[i][j] = (f32x4){0.f, 0.f, 0.f, 0.f};

  const unsigned short* Ab = A + (size_t)m0 * K;
  const unsigned short* Bb = Bt + (size_t)n0 * K;

  for (int k0 = 0; k0 < K; k0 += 32) {
    __syncthreads();
#pragma unroll
    for (int i = 0; i < 2; ++i) {
      int idx = i * 256 + tid;
      int row = idx >> 2;
      int off = (idx & 3) << 3;
      gload_lds16(Ab + (size_t)row * K + k0 + off, As + row * 32 + off);
      gload_lds16(Bb + (size_t)row * K + k0 + off, Bs + row * 32 + off);
    }
    __syncthreads();

    bf16x8 af[4], bfr[4];
#pragma unroll
    for (int mi = 0; mi < 4; ++mi)
      af[mi] = *reinterpret_cast<const bf16x8*>(As + (wr * 64 + mi * 16 + lr) * 32 + kb * 8);
#pragma unroll
    for (int ni = 0; ni < 4; ++ni)
      bfr[ni] = *reinterpret_cast<const bf16x8*>(Bs + (wc * 64 + ni * 16 + lr) * 32 + kb * 8);
#pragma unroll
    for (int mi = 0; mi < 4; ++mi)
#pragma unroll
      for (int ni = 0; ni < 4; ++ni)
        acc[mi][ni] = __builtin_amdgcn_mfma_f32_16x16x32_bf16(af[mi], bfr[ni], acc[mi][ni], 0, 0, 0);
  }

#pragma unroll
  for (int mi = 0; mi < 4; ++mi)
#pragma unroll
    for (int ni = 0; ni < 4; ++ni)
#pragma unroll
      for (int r = 0; r < 4; ++r) {
        int row = m0 + wr * 64 + mi * 16 + kb * 4 + r;
        int col = n0 + wc * 64 + ni * 16 + lr;
        store_out(&C[(size_t)row * N + col], acc[mi][ni][r]);
      }
}

// ---------------- 256-tile 8-wave 4-phase GEMM (T2+T3+T4+T5) — Q/O proj ----------
#define STAGE_HALF(dstBase, Sp, k0, h)                                           \
  {                                                                              \
    _Pragma("unroll")                                                            \
    for (int i_ = 0; i_ < 2; ++i_) {                                             \
      int c_ = i_ * 512 + tid;                                                   \
      int rl_ = c_ >> 3, ch_ = c_ & 7;                                           \
      int row_ = (h) * 128 + rl_;                                                \
      gload_lds16((Sp) + (size_t)row_ * K + (k0) + ((ch_ ^ (row_ & 7)) << 3),    \
                  (char*)(dstBase) + row_ * 128 + ch_ * 16);                     \
    }                                                                            \
  }
#define LDF(buf, R, sw) \
  (*reinterpret_cast<const bf16x8*>((const char*)(buf) + (R) * 128 + (sw)))
#define PHASE_SYNC()                                        \
  __builtin_amdgcn_s_barrier();                             \
  asm volatile("s_waitcnt lgkmcnt(0)" ::: "memory");        \
  __builtin_amdgcn_sched_barrier(0);

template <typename OutT>
__global__ __launch_bounds__(512, 1) void gemm256(const unsigned short* __restrict__ A,
                                                  const unsigned short* __restrict__ Bt,
                                                  OutT* __restrict__ C, int M, int N, int K) {
  __shared__ unsigned short Asl[2][256 * 64];
  __shared__ unsigned short Bsl[2][256 * 64];
  const int tid = threadIdx.x;
  const int lane = tid & 63;
  const int wave = tid >> 6;       // 0..7
  const int wr = wave >> 2;        // 0..1  (M)
  const int wc = wave & 3;         // 0..3  (N)
  const int lr = lane & 15, kb = lane >> 4;

  int nwg = gridDim.x, wg = blockIdx.x;
  int swz = (nwg % 8 == 0) ? ((wg & 7) * (nwg >> 3) + (wg >> 3)) : wg;
  const int nbn = N >> 8;
  const int bm = swz / nbn, bn = swz % nbn;
  const int m0 = bm << 8, n0 = bn << 8;

  const unsigned short* Ab = A + (size_t)m0 * K;
  const unsigned short* Bb = Bt + (size_t)n0 * K;

  f32x4 acc[8][4];
#pragma unroll
  for (int i = 0; i < 8; ++i)
#pragma unroll
    for (int j = 0; j < 4; ++j) acc[i][j] = (f32x4){0.f, 0.f, 0.f, 0.f};

  const int sw0 = ((kb) ^ (lr & 7)) << 4;
  const int sw1 = ((4 + kb) ^ (lr & 7)) << 4;

  STAGE_HALF(Asl[0], Ab, 0, 0); STAGE_HALF(Asl[0], Ab, 0, 1);
  STAGE_HALF(Bsl[0], Bb, 0, 0); STAGE_HALF(Bsl[0], Bb, 0, 1);
  __syncthreads();

  const int nt = K >> 6;
  bf16x8 af[4], bfr[4];

#pragma unroll 1
  for (int t = 0; t < nt; ++t) {
    const unsigned short* Acur = Asl[t & 1];
    const unsigned short* Bcur = Bsl[t & 1];
    unsigned short* Anxt = Asl[(t + 1) & 1];
    unsigned short* Bnxt = Bsl[(t + 1) & 1];
    const int k0n = (t + 1) << 6;
    const bool pf = (t + 1 < nt);

    // ---- phase 0: (mh=0, kk=0); stage A(t+1)
#pragma unroll
    for (int ni = 0; ni < 4; ++ni) bfr[ni] = LDF(Bcur, wc * 64 + ni * 16 + lr, sw0);
#pragma unroll
    for (int mi = 0; mi < 4; ++mi) af[mi] = LDF(Acur, wr * 128 + mi * 16 + lr, sw0);
    if (pf) { STAGE_HALF(Anxt, Ab, k0n, 0); STAGE_HALF(Anxt, Ab, k0n, 1); }
    PHASE_SYNC();
    __builtin_amdgcn_s_setprio(1);
#pragma unroll
    for (int mi = 0; mi < 4; ++mi)
#pragma unroll
      for (int ni = 0; ni < 4; ++ni)
        acc[mi][ni] = __builtin_amdgcn_mfma_f32_16x16x32_bf16(af[mi], bfr[ni], acc[mi][ni], 0, 0, 0);
    __builtin_amdgcn_s_setprio(0);
    __builtin_amdgcn_s_barrier();

    // ---- phase 1: (mh=1, kk=0); stage B(t+1)
#pragma unroll
    for (int mi = 0; mi < 4; ++mi) af[mi] = LDF(Acur, wr * 128 + (mi + 4) * 16 + lr, sw0);
    if (pf) { STAGE_HALF(Bnxt, Bb, k0n, 0); STAGE_HALF(Bnxt, Bb, k0n, 1); }
    PHASE_SYNC();
    __builtin_amdgcn_s_setprio(1);
#pragma unroll
    for (int mi = 0; mi < 4; ++mi)
#pragma unroll
      for (int ni = 0; ni < 4; ++ni)
        acc[mi + 4][ni] = __builtin_amdgcn_mfma_f32_16x16x32_bf16(af[mi], bfr[ni], acc[mi + 4][ni], 0, 0, 0);
    __builtin_amdgcn_s_setprio(0);
    __builtin_amdgcn_s_barrier();

    // ---- phase 2: (mh=0, kk=1)
#pragma unroll
    for (int ni = 0; ni < 4; ++ni) bfr[ni] = LDF(Bcur, wc * 64 + ni * 16 + lr, sw1);
#pragma unroll
    for (int mi = 0; mi < 4; ++mi) af[mi] = LDF(Acur, wr * 128 + mi * 16 + lr, sw1);
    PHASE_SYNC();
    __builtin_amdgcn_s_setprio(1);
#pragma unroll
    for (int mi = 0; mi < 4; ++mi)
#pragma unroll
      for (int ni = 0; ni < 4; ++ni)
        acc[mi][ni] = __builtin_amdgcn_mfma_f32_16x16x32_bf16(af[mi], bfr[ni], acc[mi][ni], 0, 0, 0);
    __builtin_amdgcn_s_setprio(0);
    __builtin_amdgcn_s_barrier();

    // ---- phase 3: (mh=1, kk=1)
#pragma unroll
    for (int mi = 0; mi < 4; ++mi) af[mi] = LDF(Acur, wr * 128 + (mi + 4) * 16 + lr, sw1);
    PHASE_SYNC();
    __builtin_amdgcn_s_setprio(1);
#pragma unroll
    for (int mi = 0; mi < 4; ++mi)
#pragma unroll
      for (int ni = 0; ni < 4; ++ni)
        acc[mi + 4][ni] = __builtin_amdgcn_mfma_f32_16x16x32_bf16(af[mi], bfr[ni], acc[mi + 4][ni], 0, 0, 0);
    __builtin_amdgcn_s_setprio(0);
    __builtin_amdgcn_s_barrier();

    if (pf) asm volatile("s_waitcnt vmcnt(0)" ::: "memory");
    __builtin_amdgcn_s_barrier();
  }

#pragma unroll
  for (int mi = 0; mi < 8; ++mi)
#pragma unroll
    for (int ni = 0; ni < 4; ++ni)
#pragma unroll
      for (int r = 0; r < 4; ++r) {
        int row = m0 + wr * 128 + mi * 16 + kb * 4 + r;
        int col = n0 + wc * 64 + ni * 16 + lr;
        store_out(&C[(size_t)row * N + col], acc[mi][ni][r]);
      }
}

// ---------------- flash attention (causal, GQA 32/8, D=128) ----------------
// SWAPPED QK^T: sf = mfma(kf, qf) -> lane holds S^T[key=kb*4+r (frag ki)][q=lr].
// Per-lane scalar online softmax (2 shuffles/reduce), defer-max (THR=8, wave vote).
// K LDS: linear rows, SOURCE chunk-XOR-swizzled. V: direct global reads (stride KV2).
// P: [q][key] per-wave LDS, 2x packed ushort4 writes; pf b128 read (proven layout).
__global__ __launch_bounds__(256) void attn_fwd(const unsigned short* __restrict__ Q,
                                                const unsigned short* __restrict__ KV,
                                                unsigned short* __restrict__ O) {
  __shared__ unsigned short Ks[32 * 128];
  __shared__ unsigned short Ps[4][16 * 32];
  const int tid = threadIdx.x, lane = tid & 63, wave = tid >> 6;
  const int lr = lane & 15, kb = lane >> 4;
  const int pr = blockIdx.x;           // 0..15 (pair index)
  const int bh = blockIdx.y;           // 0..63
  const int b = bh >> 5, h = bh & 31, kvh = h >> 2;
  const unsigned short* Qp = Q + (size_t)b * S_LEN * HID_DIM + (size_t)h * HD;
  const unsigned short* Kp = KV + (size_t)b * S_LEN * KV2 + (size_t)kvh * HD;
  const unsigned short* Vp = Kp + KV_DIM;
  unsigned short* Op = O + (size_t)b * S_LEN * HID_DIM + (size_t)h * HD;

#pragma unroll 1
  for (int pass = 0; pass < 2; ++pass) {
    const int qt = pass ? pr : 31 - pr;
    const int q0 = qt * 64;

    // Q fragments (B-frag for swapped QK^T: lane lr = q, k = kb*8+j)
    bf16x8 qf[4];
    const int qrow = q0 + wave * 16 + lr;
#pragma unroll
    for (int dc = 0; dc < 4; ++dc)
      qf[dc] = *reinterpret_cast<const bf16x8*>(Qp + (size_t)qrow * HID_DIM + dc * 32 + kb * 8);

    f32x4 of[8];
#pragma unroll
    for (int i = 0; i < 8; ++i) of[i] = (f32x4){0.f, 0.f, 0.f, 0.f};
    float mrow = -3.0e38f, lrow = 0.f;   // per-lane scalars: q = lr

    const int kvend = q0 + 64;
    for (int kv0 = 0; kv0 < kvend; kv0 += 32) {
      __syncthreads();
#pragma unroll
      for (int i = 0; i < 2; ++i) {
        int c = i * 256 + tid;
        int key = c >> 4;
        int ch = (c & 15) ^ (key & 7);
        gload_lds16(Kp + (size_t)(kv0 + key) * KV2 + ch * 8, Ks + c * 8);
      }
      __syncthreads();

      // --- S^T = K Q^T : A-frag = kf (lane lr = key), B-frag = qf (lane lr = q)
      f32x4 sf[2];
      sf[0] = (f32x4){0.f, 0.f, 0.f, 0.f};
      sf[1] = (f32x4){0.f, 0.f, 0.f, 0.f};
#pragma unroll
      for (int ki = 0; ki < 2; ++ki)
#pragma unroll
        for (int dc = 0; dc < 4; ++dc) {
          int key = ki * 16 + lr;
          bf16x8 kf = *reinterpret_cast<const bf16x8*>(
              Ks + key * 128 + (((dc * 4 + kb) ^ (lr & 7)) << 3));
          sf[ki] = __builtin_amdgcn_mfma_f32_16x16x32_bf16(kf, qf[dc], sf[ki], 0, 0, 0);
        }

      // --- mask: lane's scores are (key = kv0 + ki*16 + kb*4 + r, q = qrow)
      const int thr = qrow - kv0;
      float s[8];
#pragma unroll
      for (int ki = 0; ki < 2; ++ki)
#pragma unroll
        for (int r = 0; r < 4; ++r) {
          int ko = ki * 16 + kb * 4 + r;
          s[ki * 4 + r] = (ko > thr) ? -3.0e38f : sf[ki][r];
        }

      // --- per-lane online softmax (q = lr), 2-shuffle reduces
      float m8 = fmaxf(fmaxf(fmaxf(s[0], s[1]), fmaxf(s[2], s[3])),
                       fmaxf(fmaxf(s[4], s[5]), fmaxf(s[6], s[7])));
      m8 = fmaxf(m8, __shfl_xor(m8, 16));
      m8 = fmaxf(m8, __shfl_xor(m8, 32));
      if (__any(m8 > mrow + 8.0f)) {      // rescale path (first tile + rare growth)
        float mn = fmaxf(mrow, m8);
        float corr = __expf(mrow - mn);
        lrow *= corr;
#pragma unroll
        for (int r = 0; r < 4; ++r) {
          float cr = __shfl(corr, kb * 4 + r);   // corr for q = kb*4+r (of row layout)
#pragma unroll
          for (int dc2 = 0; dc2 < 8; ++dc2) of[dc2][r] *= cr;
        }
        mrow = mn;
      }
      float rs = 0.f;
      ushort4 pw[2];
#pragma unroll
      for (int ki = 0; ki < 2; ++ki) {
        unsigned short* pp = (unsigned short*)&pw[ki];
#pragma unroll
        for (int r = 0; r < 4; ++r) {
          float p = __expf(s[ki * 4 + r] - mrow);   // bounded by e^8
          rs += p;
          pp[r] = f2b(p);
        }
      }
      rs += __shfl_xor(rs, 16);
      rs += __shfl_xor(rs, 32);
      lrow += rs;

      // --- P write: [q=lr][key], two packed b64 per lane
      *reinterpret_cast<ushort4*>(&Ps[wave][lr * 32 + kb * 4])      = pw[0];
      *reinterpret_cast<ushort4*>(&Ps[wave][lr * 32 + 16 + kb * 4]) = pw[1];
      asm volatile("s_waitcnt lgkmcnt(0)" ::: "memory");
      __builtin_amdgcn_sched_barrier(0);

      // --- O += P V : pf A-frag (lane lr = q, key = kb*8+j), vf direct global
      bf16x8 pf = *reinterpret_cast<const bf16x8*>(&Ps[wave][lr * 32 + kb * 8]);
      const unsigned short* Vr0 = Vp + (size_t)(kv0 + kb * 8) * KV2;
#pragma unroll
      for (int g = 0; g < 2; ++g) {
        bf16x8 vf[4];
#pragma unroll
        for (int dh = 0; dh < 4; ++dh) {
          int dc2 = g * 4 + dh;
#pragma unroll
          for (int j = 0; j < 8; ++j)
            vf[dh][j] = (short)Vr0[(size_t)j * KV2 + dc2 * 16 + lr];
        }
#pragma unroll
        for (int dh = 0; dh < 4; ++dh)
          of[g * 4 + dh] = __builtin_amdgcn_mfma_f32_16x16x32_bf16(pf, vf[dh], of[g * 4 + dh], 0, 0, 0);
      }
    }

    // --- normalize + write (of row q = kb*4+r; lrow lives at lane lr = q)
    float linv[4];
#pragma unroll
    for (int r = 0; r < 4; ++r) linv[r] = 1.0f / __shfl(lrow, kb * 4 + r);
#pragma unroll
    for (int dc2 = 0; dc2 < 8; ++dc2)
#pragma unroll
      for (int r = 0; r < 4; ++r) {
        int qg = q0 + wave * 16 + kb * 4 + r;
        Op[(size_t)qg * HID_DIM + dc2 * 16 + lr] = f2b(of[dc2][r] * linv[r]);
      }
  }
}

// ---------------- launch ----------------
extern "C" void kernel_launch(void* const* d_in, const int* in_sizes, int n_in,
                              void* d_out, int out_size, void* d_ws, size_t ws_size,
                              hipStream_t stream) {
  const float* x  = (const float*)d_in[0];
  const float* Wq = (const float*)d_in[2];
  const float* Wk = (const float*)d_in[3];
  const float* Wv = (const float*)d_in[4];
  const float* Wo = (const float*)d_in[5];
  float* out = (float*)d_out;

  char* ws = (char*)d_ws;
  unsigned short* xb  = (unsigned short*)(ws + 0);          // 33.5MB (later reused as AO)
  unsigned short* wtb = (unsigned short*)(ws + 33554432);   // Wq^T, later Wo^T
  unsigned short* wkt = (unsigned short*)(ws + 67108864);   // Wk^T | Wv^T contiguous = Wkv^T
  unsigned short* wvt = (unsigned short*)(ws + 75497472);
  unsigned short* KVb = (unsigned short*)(ws + 117440512);  // [4096][2048] fused K|V
  float* cosT = (float*)(ws + 134217728);
  float* sinT = (float*)(ws + 134742016);
  unsigned short* Qb  = (unsigned short*)(ws + 83886080);
  unsigned short* AO  = xb;  // alias: x dead after KV projection

  cvt_f32_bf16<<<16384, 256, 0, stream>>>(x, xb, (BS_ROWS * HID_DIM) / 4);
  transpose_cvt<<<dim3(128, 128), dim3(32, 8), 0, stream>>>(Wq, wtb, HID_DIM, HID_DIM);
  transpose_cvt<<<dim3(32, 128), dim3(32, 8), 0, stream>>>(Wk, wkt, HID_DIM, KV_DIM);
  transpose_cvt<<<dim3(32, 128), dim3(32, 8), 0, stream>>>(Wv, wvt, HID_DIM, KV_DIM);
  rope_table_k<<<512, 256, 0, stream>>>(cosT, sinT);

  gemm256<unsigned short><<<256, 512, 0, stream>>>(xb, wtb, Qb, BS_ROWS, HID_DIM, HID_DIM);
  gemm_bt<unsigned short><<<512, 256, 0, stream>>>(xb, wkt, KVb, BS_ROWS, KV2, HID_DIM);  // fused K|V

  transpose_cvt<<<dim3(128, 128), dim3(32, 8), 0, stream>>>(Wo, wtb, HID_DIM, HID_DIM);

  rope_apply_k<<<32768, 256, 0, stream>>>(Qb, cosT, sinT, NHEADS, HID_DIM,
                                          0.08838834764831843f, BS_ROWS * NHEADS * 64);
  rope_apply_k<<<8192, 256, 0, stream>>>(KVb, cosT, sinT, NKVH, KV2, 1.0f,
                                         BS_ROWS * NKVH * 64);

  attn_fwd<<<dim3(16, 64), 256, 0, stream>>>(Qb, KVb, AO);

  gemm256<float><<<256, 512, 0, stream>>>(AO, wtb, out, BS_ROWS, HID_DIM, HID_DIM);
}